// Round 1
// baseline (113.944 us; speedup 1.0000x reference)
//
#include <hip/hip_runtime.h>

// BPNet fused forward: E=16384 edges, ORDER=3, D=13, RANK=128, NUM_PARAMS=4.
// One wave (64 lanes) per edge; lane owns rank channels {lane, lane+64}.
// NUM_ITERS loop in reference is idempotent (t never updated, node_msg reset
// each iter) -> compute exactly one iteration.

#define DD 13
#define RK 128
#define OD 3
#define NP 4

__global__ __launch_bounds__(256) void bpnet_fused(
    const float* __restrict__ nodes,      // [N, 13]
    const float* __restrict__ bp_params,  // [4, 13, 128]
    const float* __restrict__ bp_bias,    // [4, 1, 128]
    const float* __restrict__ ho_params,  // [3, 4, 128, 13]
    const float* __restrict__ ho_bias,    // [3, 4, 1, 13]
    const int*   __restrict__ edges,      // [E, 3]
    const int*   __restrict__ edge_types, // [E, 3]
    float*       __restrict__ out,        // [N, 13] (pre-zeroed)
    int E)
{
    const int lane = threadIdx.x & 63;
    const int wv   = threadIdx.x >> 6;
    const int e    = blockIdx.x * 4 + wv;
    if (e >= E) return;

    int et[OD], tg[OD];
#pragma unroll
    for (int o = 0; o < OD; ++o) {
        et[o] = edge_types[e * OD + o];
        tg[o] = edges[e * OD + o];
    }

    // Stage 1: t[o][r] = relu(nodes[tg[o],:] @ bp_params[et[o],:,:] + bias)
    // lane handles r = lane and r = lane + 64.
    float t0[OD], t1[OD];
#pragma unroll
    for (int o = 0; o < OD; ++o) {
        const int ty = et[o];
        const float* W  = bp_params + ty * DD * RK;
        const float* nr = nodes + (size_t)tg[o] * DD;
        float s0 = bp_bias[ty * RK + lane];
        float s1 = bp_bias[ty * RK + 64 + lane];
#pragma unroll
        for (int d = 0; d < DD; ++d) {
            float rv = nr[d];  // wave-uniform address, L1/L2-hot
            s0 = fmaf(rv, W[d * RK + lane], s0);
            s1 = fmaf(rv, W[d * RK + 64 + lane], s1);
        }
        t0[o] = fmaxf(s0, 0.f);
        t1[o] = fmaxf(s1, 0.f);
    }

    // Stage 2: for each slot i, fact = prod of other slots' t; msg = fact @ W_i
#pragma unroll
    for (int i = 0; i < OD; ++i) {
        const int j = (i + 1) % OD, k = (i + 2) % OD;
        const float f0 = t0[j] * t0[k];
        const float f1 = t1[j] * t1[k];
        const int ty = et[i];
        const float* W  = ho_params + (size_t)(i * NP + ty) * RK * DD;
        const float* W0 = W + lane * DD;
        const float* W1 = W + (lane + 64) * DD;
        float msg = 0.f;
#pragma unroll
        for (int d = 0; d < DD; ++d) {
            float v = fmaf(f1, W1[d], f0 * W0[d]);
            // 64-lane butterfly: every lane ends with the full sum over r
            v += __shfl_xor(v, 32, 64);
            v += __shfl_xor(v, 16, 64);
            v += __shfl_xor(v, 8, 64);
            v += __shfl_xor(v, 4, 64);
            v += __shfl_xor(v, 2, 64);
            v += __shfl_xor(v, 1, 64);
            if (lane == d) msg = v;  // keep d-th sum in lane d
        }
        if (lane < DD) {
            msg += ho_bias[(i * NP + ty) * DD + lane];
            atomicAdd(out + (size_t)tg[i] * DD + lane, msg);
        }
    }
}

extern "C" void kernel_launch(void* const* d_in, const int* in_sizes, int n_in,
                              void* d_out, int out_size, void* d_ws, size_t ws_size,
                              hipStream_t stream) {
    const float* nodes      = (const float*)d_in[0];
    const float* bp_params  = (const float*)d_in[1];
    const float* bp_bias    = (const float*)d_in[2];
    const float* ho_params  = (const float*)d_in[3];
    const float* ho_bias    = (const float*)d_in[4];
    const int*   edges      = (const int*)d_in[5];
    const int*   edge_types = (const int*)d_in[6];
    // d_in[7] atoms, d_in[8] atom_edges: unused in BT mode
    float* out = (float*)d_out;

    const int E = in_sizes[5] / OD;

    // out is poisoned 0xAA before every timed call — zero it for the atomics.
    hipMemsetAsync(out, 0, (size_t)out_size * sizeof(float), stream);

    const int blocks = (E + 3) / 4;  // 4 waves (edges) per 256-thread block
    bpnet_fused<<<blocks, 256, 0, stream>>>(
        nodes, bp_params, bp_bias, ho_params, ho_bias, edges, edge_types, out, E);
}